// Round 10
// baseline (479.972 us; speedup 1.0000x reference)
//
#include <hip/hip_runtime.h>

#define N 4096
#define OUTW 12288   // n_x + n_e + n_i

// ---- Kernel A: compact spike indices per input row (ordered) + sx copy ----
__global__ void compact_spikes(const float* __restrict__ X, int* __restrict__ idx,
                               int* __restrict__ cnt, float* __restrict__ out, int T) {
    int t = blockIdx.x;
    const float* row = X + (size_t)t * N;
    __shared__ int counts[256];
    int tid = threadIdx.x;
    int base = tid * 16;
    float4 r0 = *(const float4*)(row + base);
    float4 r1 = *(const float4*)(row + base + 4);
    float4 r2 = *(const float4*)(row + base + 8);
    float4 r3 = *(const float4*)(row + base + 12);
    float* orow = out + (size_t)t * OUTW + base;   // fused sx copy
    *(float4*)(orow)      = r0;
    *(float4*)(orow + 4)  = r1;
    *(float4*)(orow + 8)  = r2;
    *(float4*)(orow + 12) = r3;
    float vals[16];
    *(float4*)(vals)      = r0;
    *(float4*)(vals + 4)  = r1;
    *(float4*)(vals + 8)  = r2;
    *(float4*)(vals + 12) = r3;
    int ks[16];
    int c = 0;
    #pragma unroll
    for (int q = 0; q < 16; ++q) {
        if (vals[q] != 0.0f) ks[c++] = base + q;
    }
    counts[tid] = c;
    __syncthreads();
    int off = 0;
    for (int i = 0; i < tid; ++i) off += counts[i];
    int* op = idx + (size_t)t * N;
    for (int q = 0; q < c; ++q) op[off + q] = ks[q];
    if (tid == 255) cnt[t] = off + c;
}

// ---- Fused time-sliced kernel -----------------------------------------------
// block 0: rec steps [ca, cb) -- all XW rows [ca, cb) were gathered by the
//          PREVIOUS kernel in the stream (no inter-block sync needed).
// blocks 1..(rb-ra): gather XW row r = ra + blockIdx.x - 1 (full row,
//          1024 threads x 4 cols float4), consumed by the NEXT kernel.
// Rec body = round-9 verified code (absmax 0.0) with dynamic triple-buffer
// rotation; state persists in `state` between chunks.
__global__ void __launch_bounds__(1024)
fused(const float* __restrict__ W, const int* __restrict__ idx,
      const int* __restrict__ cnt, float* __restrict__ XW,
      unsigned char* __restrict__ pk, float* __restrict__ state,
      int ra, int rb, int ca, int cb, int T) {
    __shared__ int sidx[4096];
    __shared__ unsigned int cS[3];
    const int tid = threadIdx.x;

    if (blockIdx.x == 0) {
        if (ca >= cb) return;
        const int lane = tid & 63;
        float ve[4], ref[4];
        unsigned int R, E, zp;
        unsigned char pw;
        float* st = state + (size_t)tid * 12;
        if (ca == 0) {
            #pragma unroll
            for (int q = 0; q < 4; ++q) { ve[q] = -65.0f; ref[q] = 0.0f; }
            R = 0u; E = 0u; zp = 0u; pw = 0;
            if (tid == 0) { cS[0] = 0u; cS[1] = 0u; cS[2] = 0u; }
        } else {
            float4 a = *(float4*)(st);
            float4 b = *(float4*)(st + 4);
            uint4  c = *(uint4*)(st + 8);
            ve[0] = a.x; ve[1] = a.y; ve[2] = a.z; ve[3] = a.w;
            ref[0] = b.x; ref[1] = b.y; ref[2] = b.z; ref[3] = b.w;
            R = c.x; E = c.y; zp = c.z; pw = (unsigned char)c.w;
            if (tid == 0) {
                cS[0] = 0u; cS[1] = 0u;
                cS[2] = *(unsigned int*)(state + 12 * 1024);   // S(ca-1)
            }
        }
        const float4* xwp = (const float4*)XW + tid;   // row stride 1024 float4s
        float4 xw = xwp[(size_t)ca * 1024];
        unsigned char* pkp = pk + tid;
        int prev = 2, cur = 0, nxt = 1;
        __syncthreads();

        for (int t = ca; t < cb; ++t) {
            unsigned int Sint = cS[prev];             // S(t-1), broadcast read
            if (t > 0) pkp[(size_t)(t - 1) * 1024] = pw;   // deferred store
            float4 xw_n = xw;
            if (t + 1 < cb) xw_n = xwp[(size_t)(t + 1) * 1024];
            if (tid == 0) cS[nxt] = 0u;               // counter for step t+1
            // i-phase: SWAR over 4 byte-lanes (exact shortcut, round-2 proof)
            unsigned int nz = (R | (R >> 1)) & 0x01010101u;
            unsigned int z  = (nz ^ 0x01010101u) & E;
            R = (R - nz) | (z << 1);
            int c0 = __popcll(__ballot((z & 0x000000ffu) != 0u));
            int c1 = __popcll(__ballot((z & 0x0000ff00u) != 0u));
            int c2 = __popcll(__ballot((z & 0x00ff0000u) != 0u));
            int c3 = __popcll(__ballot((z & 0xff000000u) != 0u));
            if (lane == 0) atomicAdd(&cS[cur], (unsigned int)(c0 + c1 + c2 + c3));
            // e-phase: float exprs match verified rounds 3/5/9
            float Sf  = (float)Sint;
            float Sf1 = Sf - 1.0f;                    // exact integer
            const float xq[4] = {xw.x, xw.y, xw.z, xw.w};
            unsigned int sbits = 0u;
            #pragma unroll
            for (int q = 0; q < 4; ++q) {
                unsigned int bq = (zp >> (q * 8)) & 1u;     // s_i(t-1) bit
                float dS = bq ? Sf1 : Sf;       // == Sf - si_f[q], bit-exact
                float in_e = xq[q] - 17.5f * dS;            // exact product
                float in_sel = (ref[q] <= 0.0f) ? in_e : 0.0f;
                float v = ve[q] + 0.01f * (-65.0f - ve[q]) + in_sel;
                float rc = fmaxf(ref[q] - 1.0f, 0.0f);
                int s = (v >= -52.0f) ? 1 : 0;
                ref[q] = s ? 5.0f : rc;
                ve[q]  = s ? -65.0f : v;
                sbits |= (unsigned int)s << q;
            }
            E = (sbits * 0x00204081u) & 0x01010101u;     // bits0..3 -> bytes
            unsigned int znib = (z * 0x10204080u) >> 24; // bytes -> bits4..7
            pw = (unsigned char)(sbits | znib);
            zp = z;
            xw = xw_n;
            int tmp = prev; prev = cur; cur = nxt; nxt = tmp;
            __syncthreads();
        }
        // flush last word of this chunk (re-stored idempotently by next chunk)
        pkp[(size_t)(cb - 1) * 1024] = pw;
        if (cb < T) {   // save state for next chunk
            float4 a = {ve[0], ve[1], ve[2], ve[3]};
            float4 b = {ref[0], ref[1], ref[2], ref[3]};
            uint4  c = {R, E, zp, (unsigned int)pw};
            *(float4*)(st)     = a;
            *(float4*)(st + 4) = b;
            *(uint4*)(st + 8)  = c;
            if (tid == 0) *(unsigned int*)(state + 12 * 1024) = cS[prev];
        }
        return;
    }

    // ---------------- gather: one full XW row per block ----------------
    int r = ra + (int)blockIdx.x - 1;
    if (r >= rb) return;
    int col = tid * 4;
    float4 acc = {0.f, 0.f, 0.f, 0.f};
    if (r > 0) {
        int c = cnt[r - 1];
        const int* ip = idx + (size_t)(r - 1) * N;
        for (int s = tid; s < c; s += 1024) sidx[s] = ip[s];
        __syncthreads();
        int s = 0;
        for (; s + 4 <= c; s += 4) {                 // strict ascending order
            int k0 = sidx[s], k1 = sidx[s + 1], k2 = sidx[s + 2], k3 = sidx[s + 3];
            float4 w0 = *(const float4*)(W + (size_t)k0 * N + col);
            float4 w1 = *(const float4*)(W + (size_t)k1 * N + col);
            float4 w2 = *(const float4*)(W + (size_t)k2 * N + col);
            float4 w3 = *(const float4*)(W + (size_t)k3 * N + col);
            acc.x += w0.x; acc.y += w0.y; acc.z += w0.z; acc.w += w0.w;
            acc.x += w1.x; acc.y += w1.y; acc.z += w1.z; acc.w += w1.w;
            acc.x += w2.x; acc.y += w2.y; acc.z += w2.z; acc.w += w2.w;
            acc.x += w3.x; acc.y += w3.y; acc.z += w3.z; acc.w += w3.w;
        }
        for (; s < c; ++s) {
            int k = sidx[s];
            float4 w0 = *(const float4*)(W + (size_t)k * N + col);
            acc.x += w0.x; acc.y += w0.y; acc.z += w0.z; acc.w += w0.w;
        }
    }
    *(float4*)(XW + (size_t)r * N + col) = acc;
}

// ---- Kernel E: expand packed spike bits -> f32 output ----------------------
__global__ void expand(const unsigned char* __restrict__ pk, float* __restrict__ out, int T) {
    int i = blockIdx.x * 256 + threadIdx.x;   // [0, T*1024)
    if (i >= T * 1024) return;
    int t = i >> 10;
    int g = i & 1023;
    unsigned int b = pk[i];
    float* orow = out + (size_t)t * OUTW + N + (size_t)g * 4;
    float4 se4 = {(float)(b & 1u), (float)((b >> 1) & 1u),
                  (float)((b >> 2) & 1u), (float)((b >> 3) & 1u)};
    float4 si4 = {(float)((b >> 4) & 1u), (float)((b >> 5) & 1u),
                  (float)((b >> 6) & 1u), (float)((b >> 7) & 1u)};
    *(float4*)orow = se4;
    *(float4*)(orow + N) = si4;
}

extern "C" void kernel_launch(void* const* d_in, const int* in_sizes, int n_in,
                              void* d_out, int out_size, void* d_ws, size_t ws_size,
                              hipStream_t stream) {
    const float* X   = (const float*)d_in[0];   // [T, 4096]
    const float* Wxe = (const float*)d_in[1];   // [4096, 4096]
    int T = in_sizes[0] / N;
    float* out = (float*)d_out;

    // ws layout (footprint identical to proven rounds 1-9):
    //   XW  float[T*N] @ 0
    //   idx int[T*N]   @ T*N*4
    //     - pk overlays idx bytes [0, T*1024)            (<= idx row 32)
    //     - state overlays idx rows 40..43 (49156 B)     (read only by fused_0,
    //       which precedes the first state write at end of fused_1)
    //   cnt int[T]     @ 2*T*N*4
    float* XW = (float*)d_ws;
    int* idx  = (int*)((char*)d_ws + (size_t)T * N * 4);
    int* cnt  = (int*)((char*)d_ws + (size_t)2 * T * N * 4);
    unsigned char* pk = (unsigned char*)idx;
    float* state = (float*)((char*)idx + 40 * 16384);

    compact_spikes<<<T, 256, 0, stream>>>(X, idx, cnt, out, T);

    const int C = 100;                       // chunk size (5 chunks at T=500)
    int nch = (T + C - 1) / C;
    for (int i = 0; i <= nch; ++i) {
        int ra = i * C, rb = (i + 1) * C;    // gather rows for NEXT kernel
        if (ra > T) ra = T;
        if (rb > T) rb = T;
        int ca = (i - 1) * C, cb = i * C;    // rec steps (rows from PREV kernel)
        if (ca < 0) ca = 0;
        if (cb > T) cb = T;
        if (i == 0) { ca = cb = 0; }
        int grid = 1 + (rb - ra);
        fused<<<grid, 1024, 0, stream>>>(Wxe, idx, cnt, XW, pk, state,
                                         ra, rb, ca, cb, T);
    }

    expand<<<(T * 1024 + 255) / 256, 256, 0, stream>>>(pk, out, T);
}